// Round 2
// baseline (344.894 us; speedup 1.0000x reference)
//
#include <hip/hip_runtime.h>
#include <stdint.h>

#define NUM_CLASSES 16
#define HW (512 * 512)            // 262144 = 2^18
#define NPIX (8 * HW)             // 2,097,152 pixels
#define NVEC (NPIX / 4)           // 524,288 float4-groups
#define HIST_BINS (NUM_CLASSES * NUM_CLASSES)  // 256
#define NBLOCKS 1024

// ext_vector types so __builtin_nontemporal_load accepts them
typedef float floatx4 __attribute__((ext_vector_type(4)));
typedef int   intx4   __attribute__((ext_vector_type(4)));

// Fused kernel: per-pixel argmax over 16 class planes + joint (pred,target)
// histogram, with the finalize (score computation) fused in via the
// last-block-done pattern. This removes the separate finalize launch and the
// full-drain -> launch gap between the two kernels.
//
// Memory-bound: 16 coalesced nt float4 streams + 1 int4 target stream
// (142.6 MB total, ~23 us at 6.3 TB/s achievable). 1024 blocks x 256 threads
// = 4 blocks/CU (launch_bounds (256,4) caps VGPR <=128) = 16 waves/CU.
//
// ws layout: ws[0..255] = joint histogram, ws[256] = done counter.
__global__ __launch_bounds__(256, 4) void jaccard_fused_kernel(
    const float* __restrict__ pred,
    const int* __restrict__ target,
    unsigned int* __restrict__ ws,
    float* __restrict__ out) {
  __shared__ unsigned int lh[HIST_BINS];
  __shared__ bool am_last;
  lh[threadIdx.x] = 0u;  // 256 threads cover 256 bins
  __syncthreads();

  int tid = blockIdx.x * blockDim.x + threadIdx.x;
  int stride = gridDim.x * blockDim.x;

  for (int i = tid; i < NVEC; i += stride) {
    int idx4 = i << 2;                 // first pixel of this group
    int b = idx4 >> 18;                // batch index (HW = 2^18)
    int hw = idx4 & (HW - 1);          // offset within plane, multiple of 4
    const float* base = pred + (size_t)b * NUM_CLASSES * HW + hw;

    // Non-temporal: single-use streaming data; the 16 plane streams are
    // 1 MiB apart -> same L2 set index bits. nt avoids pointless L2 thrash.
    floatx4 best = __builtin_nontemporal_load((const floatx4*)base);
    int ax = 0, ay = 0, az = 0, aw = 0;
#pragma unroll
    for (int c = 1; c < NUM_CLASSES; ++c) {
      floatx4 v = __builtin_nontemporal_load((const floatx4*)(base + (size_t)c * HW));
      // strict > keeps first occurrence of the max (jnp.argmax semantics)
      if (v.x > best.x) { best.x = v.x; ax = c; }
      if (v.y > best.y) { best.y = v.y; ay = c; }
      if (v.z > best.z) { best.z = v.z; az = c; }
      if (v.w > best.w) { best.w = v.w; aw = c; }
    }

    intx4 t = __builtin_nontemporal_load((const intx4*)(target + idx4));
    atomicAdd(&lh[(ax << 4) + t.x], 1u);
    atomicAdd(&lh[(ay << 4) + t.y], 1u);
    atomicAdd(&lh[(az << 4) + t.z], 1u);
    atomicAdd(&lh[(aw << 4) + t.w], 1u);
  }

  __syncthreads();
  // Stagger flush bin by blockIdx so 1024 blocks don't hammer the same
  // ghist address in the same order (same-address atomic RMWs serialize
  // at the owning L2 channel).
  int bin = (threadIdx.x + (blockIdx.x << 4)) & (HIST_BINS - 1);
  unsigned int v = lh[bin];
  if (v) atomicAdd(&ws[bin], v);

  // --- last-block-done: release my contributions, take a ticket ---
  __threadfence();   // drain my atomic (vmcnt) + make it device-visible
  __syncthreads();   // all 256 threads' flushes are now visible
  if (threadIdx.x == 0) {
    unsigned int ticket = atomicAdd(&ws[HIST_BINS], 1u);
    am_last = (ticket == (unsigned int)(NBLOCKS - 1));
  }
  __syncthreads();
  if (!am_last) return;

  // --- finalize (runs in exactly one block, after all flushes visible) ---
  __threadfence();   // acquire side
  int l = threadIdx.x;
  // agent-scope atomic load: bypass L1 so we can't read a stale line
  lh[l] = __hip_atomic_load(&ws[l], __ATOMIC_RELAXED, __HIP_MEMORY_SCOPE_AGENT);
  __syncthreads();

  if (l < 64) {
    float score = 0.0f;
    if (l < NUM_CLASSES) {
      unsigned int cp = 0, ct = 0;
#pragma unroll
      for (int j = 0; j < NUM_CLASSES; ++j) {
        cp += lh[l * 16 + j];   // pred == l   (row sum)
        ct += lh[j * 16 + l];   // target == l (col sum)
      }
      unsigned int inter = lh[l * 17];  // pred == target == l (diagonal)
      float uni = (float)cp + (float)ct - (float)inter;
      score = (uni == 0.0f) ? 1.0f : ((float)inter / uni);
    }
    // reduce 16 partial scores in lanes 0..15 of wave 0 (others are 0)
#pragma unroll
    for (int off = 8; off >= 1; off >>= 1) score += __shfl_down(score, off, 64);
    if (l == 0) out[0] = score * (1.0f / (float)NUM_CLASSES);
  }
}

extern "C" void kernel_launch(void* const* d_in, const int* in_sizes, int n_in,
                              void* d_out, int out_size, void* d_ws, size_t ws_size,
                              hipStream_t stream) {
  const float* pred = (const float*)d_in[0];
  const int* target = (const int*)d_in[1];
  float* out = (float*)d_out;
  unsigned int* ws = (unsigned int*)d_ws;

  // d_ws is re-poisoned to 0xAA before every timed call — zero the histogram
  // (256 bins) and the done-counter (1 extra uint) each time.
  hipMemsetAsync(d_ws, 0, (HIST_BINS + 1) * sizeof(unsigned int), stream);

  // 1024 blocks x 256 threads, 2 grid-stride iterations/thread, exact
  // coverage; finalize fused into the last block to finish.
  jaccard_fused_kernel<<<NBLOCKS, 256, 0, stream>>>(pred, target, ws, out);
}

// Round 3
// 190.285 us; speedup vs baseline: 1.8125x; 1.8125x over previous
//
#include <hip/hip_runtime.h>
#include <stdint.h>

#define NUM_CLASSES 16
#define HW (512 * 512)            // 262144 = 2^18
#define NPIX (8 * HW)             // 2,097,152 pixels
#define NVEC (NPIX / 4)           // 524,288 float4-groups
#define HIST_BINS (NUM_CLASSES * NUM_CLASSES)  // 256

// ext_vector types so __builtin_nontemporal_load accepts them
typedef float floatx4 __attribute__((ext_vector_type(4)));
typedef int   intx4   __attribute__((ext_vector_type(4)));

// Kernel 1: per-pixel argmax over 16 class planes + joint (pred,target)
// histogram. Memory-bound: 16 coalesced nt float4 streams + 1 int4 target
// stream (142.6 MB, ~22 us at 6.3 TB/s). 1024 blocks x 256 threads =
// 4 blocks/CU (launch_bounds (256,4) caps VGPR at 128) = 16 waves/CU.
//
// MLP is forced explicitly: all 16 plane loads are issued into a register
// array BEFORE any compare consumes them. Round-2's fused kernel showed the
// compiler will otherwise allocate ~36 VGPRs and serialize the loads into
// ~4-deep batches, exposing full HBM latency per batch (kernel went 6x
// slower). 16 x float4 = 64 payload VGPRs + addressing fits the 128 cap.
__global__ __launch_bounds__(256, 4) void jaccard_hist_kernel(
    const float* __restrict__ pred,
    const int* __restrict__ target,
    unsigned int* __restrict__ ghist) {
  __shared__ unsigned int lh[HIST_BINS];
  lh[threadIdx.x] = 0u;  // 256 threads cover 256 bins
  __syncthreads();

  int tid = blockIdx.x * blockDim.x + threadIdx.x;
  int stride = gridDim.x * blockDim.x;

  for (int i = tid; i < NVEC; i += stride) {
    int idx4 = i << 2;                 // first pixel of this group
    int b = idx4 >> 18;                // batch index (HW = 2^18)
    int hw = idx4 & (HW - 1);          // offset within plane, multiple of 4
    const float* base = pred + (size_t)b * NUM_CLASSES * HW + hw;

    // Issue ALL plane loads first (static indices -> stays in VGPRs, §rule20),
    // plus the target load, before any compare. 17 loads in flight.
    floatx4 v[NUM_CLASSES];
#pragma unroll
    for (int c = 0; c < NUM_CLASSES; ++c)
      v[c] = __builtin_nontemporal_load((const floatx4*)(base + (size_t)c * HW));
    intx4 t = __builtin_nontemporal_load((const intx4*)(target + idx4));

    floatx4 best = v[0];
    int ax = 0, ay = 0, az = 0, aw = 0;
#pragma unroll
    for (int c = 1; c < NUM_CLASSES; ++c) {
      // strict > keeps first occurrence of the max (jnp.argmax semantics)
      if (v[c].x > best.x) { best.x = v[c].x; ax = c; }
      if (v[c].y > best.y) { best.y = v[c].y; ay = c; }
      if (v[c].z > best.z) { best.z = v[c].z; az = c; }
      if (v[c].w > best.w) { best.w = v[c].w; aw = c; }
    }

    atomicAdd(&lh[(ax << 4) + t.x], 1u);
    atomicAdd(&lh[(ay << 4) + t.y], 1u);
    atomicAdd(&lh[(az << 4) + t.z], 1u);
    atomicAdd(&lh[(aw << 4) + t.w], 1u);
  }

  __syncthreads();
  // Stagger flush bin by blockIdx so 1024 blocks don't hammer the same
  // ghist address in the same order (same-address atomic RMWs serialize
  // at the owning L2 channel).
  int bin = (threadIdx.x + (blockIdx.x << 4)) & (HIST_BINS - 1);
  unsigned int v2 = lh[bin];
  if (v2) atomicAdd(&ghist[bin], v2);
}

// Kernel 2: one wave. counts_p[c] = row sum, counts_t[c] = col sum,
// inter[c] = diagonal; score = inter/union (1.0 if union==0); out = mean.
__global__ __launch_bounds__(64) void jaccard_finalize_kernel(
    const unsigned int* __restrict__ ghist, float* __restrict__ out) {
  __shared__ unsigned int h[HIST_BINS];
  int l = threadIdx.x;  // 0..63
#pragma unroll
  for (int k = 0; k < 4; ++k) h[l + 64 * k] = ghist[l + 64 * k];
  __syncthreads();

  float score = 0.0f;
  if (l < NUM_CLASSES) {
    unsigned int cp = 0, ct = 0;
#pragma unroll
    for (int j = 0; j < NUM_CLASSES; ++j) {
      cp += h[l * 16 + j];   // pred == l
      ct += h[j * 16 + l];   // target == l
    }
    unsigned int inter = h[l * 17];  // pred == target == l
    float uni = (float)cp + (float)ct - (float)inter;
    score = (uni == 0.0f) ? 1.0f : ((float)inter / uni);
  }

  // reduce 16 partial scores living in lanes 0..15 (lanes 16..63 are 0)
#pragma unroll
  for (int off = 8; off >= 1; off >>= 1) score += __shfl_down(score, off, 64);

  if (l == 0) out[0] = score * (1.0f / (float)NUM_CLASSES);
}

extern "C" void kernel_launch(void* const* d_in, const int* in_sizes, int n_in,
                              void* d_out, int out_size, void* d_ws, size_t ws_size,
                              hipStream_t stream) {
  const float* pred = (const float*)d_in[0];
  const int* target = (const int*)d_in[1];
  float* out = (float*)d_out;
  unsigned int* ghist = (unsigned int*)d_ws;

  // d_ws is re-poisoned to 0xAA before every timed call — zero it each time.
  hipMemsetAsync(d_ws, 0, HIST_BINS * sizeof(unsigned int), stream);

  // 1024 blocks x 256 threads, 2 grid-stride iterations/thread, exact coverage.
  jaccard_hist_kernel<<<1024, 256, 0, stream>>>(pred, target, ghist);
  jaccard_finalize_kernel<<<1, 64, 0, stream>>>(ghist, out);
}